// Round 5
// baseline (436.159 us; speedup 1.0000x reference)
//
#include <hip/hip_runtime.h>

// ---------- types ----------
typedef _Float16 f16;
typedef _Float16 f16x4 __attribute__((ext_vector_type(4)));
typedef _Float16 f16x8 __attribute__((ext_vector_type(8)));
typedef float    f32x4 __attribute__((ext_vector_type(4)));
typedef unsigned int u32;
typedef u32 u32x2 __attribute__((ext_vector_type(2)));

#define N_ROWS 100000
#define NSTEP 1563        // ceil(100000/64); each step = 64 rows (16/wave)
#define GRID 512          // 2 blocks/CU resident (LDS 64KB), 3-4 steps each

// ws layout (bytes): weights only
#define W1T_OFF 0
#define W1T_BYTES (256 * 256 * 2)
#define W2T_OFF W1T_BYTES

// ---------- prep: combined, transposed f16 weights ----------
__global__ void prep_w(const float* __restrict__ wz1, const float* __restrict__ wh1,
                       const float* __restrict__ wz2, const float* __restrict__ wh2,
                       f16* __restrict__ W1T, f16* __restrict__ W2T) {
    const int b = blockIdx.x;
    if (b < 256) {                                 // W1: 65536 elems, W1T[c][k]
        int idx = b * 256 + threadIdx.x;
        int k = idx >> 8, c = idx & 255;
        const float* w = (c < 128) ? wz1 : wh1;
        int cc = c & 127;
        W1T[c * 256 + k] = (f16)(w[k * 128 + cc] + w[384 * 128 + k * 128 + cc]);
    } else {                                       // W2: 16384 elems, W2T[c][k]
        int idx = (b - 256) * 256 + threadIdx.x;
        int k = idx >> 7, c = idx & 127;
        const float* w = (c < 64) ? wz2 : wh2;
        int cc = c & 63;
        W2T[c * 128 + k] = (f16)(w[k * 64 + cc] + w[192 * 64 + k * 64 + cc]);
    }
}

// ---------- fused streaming kernel ----------
// Per wave: 16-row stripe, full pipeline L1 -> L2 -> lin, no __syncthreads in loop.
// Swapped MFMA (A = W, B = X rows): D lane&15 = row, quad*4+i = col.
__global__ __launch_bounds__(256, 2) void fused(
    const float* __restrict__ x,
    const f16* __restrict__ W1T, const f16* __restrict__ W2T,
    const float* __restrict__ bz1, const float* __restrict__ bh1,
    const float* __restrict__ bz2, const float* __restrict__ bh2,
    const float* __restrict__ wl1, const float* __restrict__ bl1,
    const float* __restrict__ wl2, const float* __restrict__ bl2,
    float* __restrict__ out)
{
    __shared__ __align__(16) f16 W1z[32768];       // 64KB: z-half of W1 in frag chunks

    const int tid = threadIdx.x, lane = tid & 63, wave = tid >> 6;
    const int ln = lane & 15, quad = lane >> 4;

    // stage W1 z-half (cols 0..127): chunk id=(mt*8+kc)*64+lane holds
    // W1T[16mt+ln][32kc+8quad .. +8]; reads are lane*16B contiguous (2-way free).
#pragma unroll
    for (int it = 0; it < 16; ++it) {
        const int id = it * 256 + tid;             // 0..4095
        const int mt = id >> 9, kc = (id >> 6) & 7, l = id & 63;
        const int q = l >> 4, n = l & 15;
        *(f16x8*)&W1z[id * 8] =
            *(const f16x8*)(W1T + (size_t)(16 * mt + n) * 256 + 32 * kc + 8 * q);
    }

    // hoisted lin-layer constants
    f16x8 bfr[2];
#pragma unroll
    for (int kc3 = 0; kc3 < 2; ++kc3)
#pragma unroll
        for (int j = 0; j < 8; ++j)
            bfr[kc3][j] = (f16)wl1[(32 * kc3 + 8 * quad + j) * 16 + ln];
    const float blv = bl1[ln], wlv = wl2[ln], bl2v = bl2[0];

    const f16* w1hp = W1T + (size_t)(128 + ln) * 256 + 8 * quad;  // h-half frag base
    const f16* w2p  = W2T + (size_t)ln * 128 + 8 * quad;

    // shfl-transpose lane indices (C-layout -> B/A-frag, within row group ln)
    const int sA = ln + ((lane & 16) << 1);        // ln + 32*(quad&1)
    const int sB = sA + 16;
    const int hi = (quad >> 1) & 1;

    __syncthreads();

#define XLOAD(dst, stp) {                                              \
    int rr = (stp) * 64 + wave * 16 + ln;                              \
    rr = rr < N_ROWS ? rr : N_ROWS - 1;                                \
    const float* xp = x + (size_t)rr * 256 + quad * 8;                 \
    _Pragma("unroll") for (int kq = 0; kq < 8; ++kq) {                 \
        dst[2*kq]   = *(const float4*)(xp + kq * 32);                  \
        dst[2*kq+1] = *(const float4*)(xp + kq * 32 + 4); } }

    float4 xc[16], xn[16];
    XLOAD(xc, (int)blockIdx.x)

    for (int s = blockIdx.x; s < NSTEP; s += GRID) {
        // convert current X stripe to f16 B-frags (waits on xc loads)
        f16x8 xf[8];
#pragma unroll
        for (int kc = 0; kc < 8; ++kc) {
            float4 a = xc[2*kc], b = xc[2*kc+1];
            xf[kc] = (f16x8){(f16)a.x,(f16)a.y,(f16)a.z,(f16)a.w,
                             (f16)b.x,(f16)b.y,(f16)b.z,(f16)b.w};
        }
        const int ns = s + GRID;
        if (ns < NSTEP) { XLOAD(xn, ns) }          // next stripe in flight
        __builtin_amdgcn_sched_barrier(0);         // pin load issue point

        // ---- P1: pre-acts for all 256 comb cols (z: LDS, h: L2) ----
        f32x4 acc[16];
#pragma unroll
        for (int m = 0; m < 16; ++m) acc[m] = (f32x4){0.f,0.f,0.f,0.f};
#pragma unroll
        for (int kc = 0; kc < 8; ++kc) {
            f16x8 wh[8];
#pragma unroll
            for (int m = 0; m < 8; ++m)
                wh[m] = *(const f16x8*)(w1hp + (size_t)m * 4096 + kc * 32);
#pragma unroll
            for (int m = 0; m < 8; ++m) {
                f16x8 wz = *(const f16x8*)&W1z[(m * 8 + kc) * 512 + lane * 8];
                acc[m] = __builtin_amdgcn_mfma_f32_16x16x32_f16(wz, xf[kc], acc[m], 0, 0, 0);
            }
#pragma unroll
            for (int m = 0; m < 8; ++m)
                acc[8+m] = __builtin_amdgcn_mfma_f32_16x16x32_f16(wh[m], xf[kc], acc[8+m], 0, 0, 0);
        }

        // P1 epilogue: gates -> g (h1 row ln, cols 16m+4quad+i)
        u32x2 gu[8];
#pragma unroll
        for (int m = 0; m < 8; ++m) {
            const int c0 = 16 * m + 4 * quad;
            float4 zb = *(const float4*)(bz1 + c0);
            float4 hb = *(const float4*)(bh1 + c0);
            f16x4 gv;
#pragma unroll
            for (int i = 0; i < 4; ++i) {
                float zp = acc[m][i]     + (&zb.x)[i];
                float hp = acc[8 + m][i] + (&hb.x)[i];
                float ex = __expf(2.0f * hp);
                float th = 1.0f - 2.0f / (ex + 1.0f);      // tanh
                float sg = 1.0f / (1.0f + __expf(zp));     // 1 - sigmoid
                gv[i] = (f16)fmaxf(th * sg, 0.0f);
            }
            gu[m] = *(u32x2*)&gv;
        }

        // shfl-transpose: C-layout g -> B-frags of h1 (row ln, k=32kc2+8quad+j)
        f16x8 bf2[4];
#pragma unroll
        for (int kc2 = 0; kc2 < 4; ++kc2) {
            u32 a0 = __shfl((int)gu[2*kc2][0],   sA), a1 = __shfl((int)gu[2*kc2][1],   sA);
            u32 b0 = __shfl((int)gu[2*kc2+1][0], sA), b1 = __shfl((int)gu[2*kc2+1][1], sA);
            u32 c0 = __shfl((int)gu[2*kc2][0],   sB), c1 = __shfl((int)gu[2*kc2][1],   sB);
            u32 d0 = __shfl((int)gu[2*kc2+1][0], sB), d1 = __shfl((int)gu[2*kc2+1][1], sB);
            u32 t[4] = { hi ? b0 : a0, hi ? b1 : a1, hi ? d0 : c0, hi ? d1 : c1 };
            bf2[kc2] = *(f16x8*)t;
        }

        // ---- P2: h2 pre-acts (W2 frags from L1/L2) ----
        f32x4 acc2[8];
#pragma unroll
        for (int m = 0; m < 8; ++m) acc2[m] = (f32x4){0.f,0.f,0.f,0.f};
#pragma unroll
        for (int kc2 = 0; kc2 < 4; ++kc2)
#pragma unroll
            for (int m = 0; m < 8; ++m) {
                f16x8 w2f = *(const f16x8*)(w2p + (size_t)m * 2048 + kc2 * 32);
                acc2[m] = __builtin_amdgcn_mfma_f32_16x16x32_f16(w2f, bf2[kc2], acc2[m], 0, 0, 0);
            }

        u32x2 g2u[4];
#pragma unroll
        for (int m = 0; m < 4; ++m) {
            const int c0 = 16 * m + 4 * quad;
            float4 zb = *(const float4*)(bz2 + c0);
            float4 hb = *(const float4*)(bh2 + c0);
            f16x4 gv;
#pragma unroll
            for (int i = 0; i < 4; ++i) {
                float zp = acc2[m][i]     + (&zb.x)[i];
                float hp = acc2[4 + m][i] + (&hb.x)[i];
                float ex = __expf(2.0f * hp);
                float th = 1.0f - 2.0f / (ex + 1.0f);
                float sg = 1.0f / (1.0f + __expf(zp));
                gv[i] = (f16)fmaxf(th * sg, 0.0f);
            }
            g2u[m] = *(u32x2*)&gv;
        }

        // ---- P3: out = relu(h2 @ wl1 + bl1) @ wl2 + bl2 ----
        f32x4 acc3 = (f32x4){0.f,0.f,0.f,0.f};
#pragma unroll
        for (int kc3 = 0; kc3 < 2; ++kc3) {
            u32 a0 = __shfl((int)g2u[2*kc3][0],   sA), a1 = __shfl((int)g2u[2*kc3][1],   sA);
            u32 b0 = __shfl((int)g2u[2*kc3+1][0], sA), b1 = __shfl((int)g2u[2*kc3+1][1], sA);
            u32 c0 = __shfl((int)g2u[2*kc3][0],   sB), c1 = __shfl((int)g2u[2*kc3][1],   sB);
            u32 d0 = __shfl((int)g2u[2*kc3+1][0], sB), d1 = __shfl((int)g2u[2*kc3+1][1], sB);
            u32 t[4] = { hi ? b0 : a0, hi ? b1 : a1, hi ? d0 : c0, hi ? d1 : c1 };
            f16x8 af3 = *(f16x8*)t;
            acc3 = __builtin_amdgcn_mfma_f32_16x16x32_f16(af3, bfr[kc3], acc3, 0, 0, 0);
        }
#pragma unroll
        for (int i = 0; i < 4; ++i) {
            float v = fmaxf(acc3[i] + blv, 0.0f) * wlv;
            v += __shfl_xor(v, 1);
            v += __shfl_xor(v, 2);
            v += __shfl_xor(v, 4);
            v += __shfl_xor(v, 8);
            if (ln == 0) {
                const int row = s * 64 + wave * 16 + quad * 4 + i;
                if (row < N_ROWS) out[row] = v + bl2v;
            }
        }

        if (ns < NSTEP) {
#pragma unroll
            for (int i2 = 0; i2 < 16; ++i2) xc[i2] = xn[i2];
        }
    }
#undef XLOAD
}

// ---------- launch ----------
extern "C" void kernel_launch(void* const* d_in, const int* in_sizes, int n_in,
                              void* d_out, int out_size, void* d_ws, size_t ws_size,
                              hipStream_t stream) {
    const float* x   = (const float*)d_in[0];
    const float* wz1 = (const float*)d_in[3];
    const float* bz1 = (const float*)d_in[4];
    const float* wh1 = (const float*)d_in[7];
    const float* bh1 = (const float*)d_in[8];
    const float* wz2 = (const float*)d_in[9];
    const float* bz2 = (const float*)d_in[10];
    const float* wh2 = (const float*)d_in[13];
    const float* bh2 = (const float*)d_in[14];
    const float* wl1 = (const float*)d_in[15];
    const float* bl1 = (const float*)d_in[16];
    const float* wl2 = (const float*)d_in[17];
    const float* bl2 = (const float*)d_in[18];

    char* ws = (char*)d_ws;
    f16* W1T = (f16*)(ws + W1T_OFF);
    f16* W2T = (f16*)(ws + W2T_OFF);
    float* out = (float*)d_out;

    prep_w<<<320, 256, 0, stream>>>(wz1, wh1, wz2, wh2, W1T, W2T);
    fused<<<GRID, 256, 0, stream>>>(x, W1T, W2T, bz1, bh1, bz2, bh2,
                                    wl1, bl1, wl2, bl2, out);
}

// Round 6
// 239.977 us; speedup vs baseline: 1.8175x; 1.8175x over previous
//
#include <hip/hip_runtime.h>

// ---------- types ----------
typedef _Float16 f16;
typedef _Float16 f16x4 __attribute__((ext_vector_type(4)));
typedef _Float16 f16x8 __attribute__((ext_vector_type(8)));
typedef float    f32x4 __attribute__((ext_vector_type(4)));

#define N_ROWS 100000
#define RT 1563           // 1563 * 64 = 100032 padded rows
#define LSX 40            // X tile f16 row stride
#define LSH1 136
#define LSH2 72

// ws: weights only
#define W1T_OFF 0
#define W1T_BYTES (256 * 256 * 2)
#define W2T_OFF W1T_BYTES

// arena (bytes): Xs dbuf | Ws dbuf ; h1s/h2s overlay after P1
#define XS0 0
#define XS1 5120
#define WS0 10240
#define WS1 26624
#define ARENA 43008
#define H1S 0             // 64*136*2 = 17408
#define H2S 17408         // 64*72*2  =  9216  -> 26624 <= ARENA

// ---------- prep: combined, transposed f16 weights ----------
__global__ void prep_w(const float* __restrict__ wz1, const float* __restrict__ wh1,
                       const float* __restrict__ wz2, const float* __restrict__ wh2,
                       f16* __restrict__ W1T, f16* __restrict__ W2T) {
    const int b = blockIdx.x;
    if (b < 256) {
        int idx = b * 256 + threadIdx.x;
        int k = idx >> 8, c = idx & 255;
        const float* w = (c < 128) ? wz1 : wh1;
        int cc = c & 127;
        W1T[c * 256 + k] = (f16)(w[k * 128 + cc] + w[384 * 128 + k * 128 + cc]);
    } else {
        int idx = (b - 256) * 256 + threadIdx.x;
        int k = idx >> 7, c = idx & 127;
        const float* w = (c < 64) ? wz2 : wh2;
        int cc = c & 63;
        W2T[c * 128 + k] = (f16)(w[k * 64 + cc] + w[192 * 64 + k * 64 + cc]);
    }
}

// ---------- fused: 64 rows/block, dbuf K-loop with ONE drain-free barrier/chunk ----------
__global__ __launch_bounds__(256, 3) void fused(
    const float* __restrict__ x,
    const f16* __restrict__ W1T, const f16* __restrict__ W2T,
    const float* __restrict__ bz1, const float* __restrict__ bh1,
    const float* __restrict__ bz2, const float* __restrict__ bh2,
    const float* __restrict__ wl1, const float* __restrict__ bl1,
    const float* __restrict__ wl2, const float* __restrict__ bl2,
    float* __restrict__ out)
{
    __shared__ __align__(16) char arena[ARENA];
    const int tid = threadIdx.x, lane = tid & 63, wave = tid >> 6;
    const int ln = lane & 15, quad = lane >> 4;
    const int r0 = blockIdx.x * 64;

    // staging thread mapping
    const int xr = tid >> 2, xcg = tid & 3;            // X: row, col-group(8 f32)
    int gxr = r0 + xr; if (gxr >= N_ROWS) gxr = N_ROWS - 1;
    const float* xp = x + (size_t)gxr * 256 + (xcg << 3);
    const int wm = tid >> 4, wn = tid & 15;            // W: col tile, col-in-tile
    const f16* wp = W1T + (size_t)tid * 256;

    // P1 wave tiles: z m-tiles {2w,2w+1}, h {2w+8,2w+9}; n-tiles 0..3 (16 rows each)
    const int Mz = 2 * wave;

    f32x4 acc[4][4];                                   // [mi][nt]
#pragma unroll
    for (int a = 0; a < 4; ++a)
#pragma unroll
        for (int b = 0; b < 4; ++b) acc[a][b] = (f32x4){0.f, 0.f, 0.f, 0.f};

    float4 pxa, pxb; f16x8 pw[4];
#define PRE(KB) { pxa = *(const float4*)(xp + (KB));  pxb = *(const float4*)(xp + (KB) + 4); \
    _Pragma("unroll") for (int q = 0; q < 4; ++q) pw[q] = *(const f16x8*)(wp + (KB) + (q << 3)); }

    PRE(0)

#pragma unroll
    for (int it = 0; it < 8; ++it) {
        f16* XsB = (f16*)(arena + ((it & 1) ? XS1 : XS0));
        f16* WsB = (f16*)(arena + ((it & 1) ? WS1 : WS0));
        // commit (consumes prefetch -> nothing in flight at the barrier)
        *(f16x8*)&XsB[xr * LSX + (xcg << 3)] =
            (f16x8){(f16)pxa.x,(f16)pxa.y,(f16)pxa.z,(f16)pxa.w,
                    (f16)pxb.x,(f16)pxb.y,(f16)pxb.z,(f16)pxb.w};
#pragma unroll
        for (int q = 0; q < 4; ++q)
            *(f16x8*)&WsB[(wm * 64 + q * 16 + wn) * 8] = pw[q];
        __syncthreads();
        if (it < 7) { PRE((it + 1) * 32) }
        __builtin_amdgcn_sched_barrier(0);             // pin prefetch issue here

        f16x8 bf[4], af[4];
#pragma unroll
        for (int nt = 0; nt < 4; ++nt)
            bf[nt] = *(const f16x8*)&XsB[(16 * nt + ln) * LSX + quad * 8];
#pragma unroll
        for (int mi = 0; mi < 4; ++mi) {
            const int M = (mi < 2) ? (Mz + mi) : (8 + Mz + mi - 2);
            af[mi] = *(const f16x8*)&WsB[(M * 64 + quad * 16 + ln) * 8];
        }
#pragma unroll
        for (int mi = 0; mi < 4; ++mi)
#pragma unroll
            for (int nt = 0; nt < 4; ++nt)
                acc[mi][nt] = __builtin_amdgcn_mfma_f32_16x16x32_f16(af[mi], bf[nt], acc[mi][nt], 0, 0, 0);
    }
#undef PRE
    __syncthreads();                                   // K-loop done; arena reused below

    // prefetch W2 frags (z col 16w+ln, h col 64+16w+ln) -- fly during epilogue
    f16x8 w2f[2][4];
#pragma unroll
    for (int kc = 0; kc < 4; ++kc) {
        w2f[0][kc] = *(const f16x8*)(W2T + (size_t)(16 * wave + ln) * 128 + kc * 32 + quad * 8);
        w2f[1][kc] = *(const f16x8*)(W2T + (size_t)(64 + 16 * wave + ln) * 128 + kc * 32 + quad * 8);
    }

    // P1 epilogue: gates -> h1s. D: col(ln)=X row, row(4quad+i)=W col.
    f16* h1s = (f16*)(arena + H1S);
#pragma unroll
    for (int mi = 0; mi < 2; ++mi) {
        const int jg0 = 32 * wave + 16 * mi + (quad << 2);
        const float4 zb = *(const float4*)(bz1 + jg0);
        const float4 hb = *(const float4*)(bh1 + jg0);
#pragma unroll
        for (int nt = 0; nt < 4; ++nt) {
            const int row = 16 * nt + ln;
            f16x4 pk;
#pragma unroll
            for (int i = 0; i < 4; ++i) {
                float zp = acc[mi][nt][i]     + (&zb.x)[i];
                float hp = acc[mi + 2][nt][i] + (&hb.x)[i];
                float ex = __expf(2.0f * hp);
                float th = 1.0f - 2.0f / (ex + 1.0f);      // tanh
                float sg = 1.0f / (1.0f + __expf(zp));     // 1 - sigmoid
                pk[i] = (f16)fmaxf(th * sg, 0.0f);
            }
            *(f16x4*)&h1s[row * LSH1 + jg0] = pk;
        }
    }
    __syncthreads();

    // ---- P2: h2 = gates(h1 @ W2); wave w: z-tile w, h-tile w+4 ----
    f32x4 acc2[2][4];
#pragma unroll
    for (int a = 0; a < 2; ++a)
#pragma unroll
        for (int b = 0; b < 4; ++b) acc2[a][b] = (f32x4){0.f, 0.f, 0.f, 0.f};
#pragma unroll
    for (int kc = 0; kc < 4; ++kc) {
        f16x8 bf[4];
#pragma unroll
        for (int nt = 0; nt < 4; ++nt)
            bf[nt] = *(const f16x8*)&h1s[(16 * nt + ln) * LSH1 + kc * 32 + quad * 8];
#pragma unroll
        for (int m = 0; m < 2; ++m)
#pragma unroll
            for (int nt = 0; nt < 4; ++nt)
                acc2[m][nt] = __builtin_amdgcn_mfma_f32_16x16x32_f16(w2f[m][kc], bf[nt], acc2[m][nt], 0, 0, 0);
    }
    __syncthreads();                                   // h1s reads done before h2s overlay

    f16* h2s = (f16*)(arena + H2S);
    {
        const int jg0 = 16 * wave + (quad << 2);
        const float4 zb = *(const float4*)(bz2 + jg0);
        const float4 hb = *(const float4*)(bh2 + jg0);
#pragma unroll
        for (int nt = 0; nt < 4; ++nt) {
            const int row = 16 * nt + ln;
            f16x4 pk;
#pragma unroll
            for (int i = 0; i < 4; ++i) {
                float zp = acc2[0][nt][i] + (&zb.x)[i];
                float hp = acc2[1][nt][i] + (&hb.x)[i];
                float ex = __expf(2.0f * hp);
                float th = 1.0f - 2.0f / (ex + 1.0f);
                float sg = 1.0f / (1.0f + __expf(zp));
                pk[i] = (f16)fmaxf(th * sg, 0.0f);
            }
            *(f16x4*)&h2s[row * LSH2 + jg0] = pk;
        }
    }
    __syncthreads();

    // ---- P3: out = relu(h2 @ wl1 + bl1) @ wl2 + bl2 ----
    const float blv = bl1[ln], wlv = wl2[ln], bl2v = bl2[0];
    f16x8 bfr[2];
#pragma unroll
    for (int kc = 0; kc < 2; ++kc)
#pragma unroll
        for (int j = 0; j < 8; ++j)
            bfr[kc][j] = (f16)wl1[(32 * kc + 8 * quad + j) * 16 + ln];

    f32x4 acc3 = (f32x4){0.f, 0.f, 0.f, 0.f};
#pragma unroll
    for (int kc = 0; kc < 2; ++kc) {
        f16x8 af = *(const f16x8*)&h2s[(16 * wave + ln) * LSH2 + kc * 32 + quad * 8];
        acc3 = __builtin_amdgcn_mfma_f32_16x16x32_f16(af, bfr[kc], acc3, 0, 0, 0);
    }
#pragma unroll
    for (int i = 0; i < 4; ++i) {
        float v = fmaxf(acc3[i] + blv, 0.0f) * wlv;
        v += __shfl_xor(v, 1);
        v += __shfl_xor(v, 2);
        v += __shfl_xor(v, 4);
        v += __shfl_xor(v, 8);
        if (ln == 0) {
            const int row = r0 + 16 * wave + (quad << 2) + i;
            if (row < N_ROWS) out[row] = v + bl2v;
        }
    }
}

// ---------- launch ----------
extern "C" void kernel_launch(void* const* d_in, const int* in_sizes, int n_in,
                              void* d_out, int out_size, void* d_ws, size_t ws_size,
                              hipStream_t stream) {
    const float* x   = (const float*)d_in[0];
    const float* wz1 = (const float*)d_in[3];
    const float* bz1 = (const float*)d_in[4];
    const float* wh1 = (const float*)d_in[7];
    const float* bh1 = (const float*)d_in[8];
    const float* wz2 = (const float*)d_in[9];
    const float* bz2 = (const float*)d_in[10];
    const float* wh2 = (const float*)d_in[13];
    const float* bh2 = (const float*)d_in[14];
    const float* wl1 = (const float*)d_in[15];
    const float* bl1 = (const float*)d_in[16];
    const float* wl2 = (const float*)d_in[17];
    const float* bl2 = (const float*)d_in[18];

    char* ws = (char*)d_ws;
    f16* W1T = (f16*)(ws + W1T_OFF);
    f16* W2T = (f16*)(ws + W2T_OFF);
    float* out = (float*)d_out;

    prep_w<<<320, 256, 0, stream>>>(wz1, wh1, wz2, wh2, W1T, W2T);
    fused<<<RT, 256, 0, stream>>>(x, W1T, W2T, bz1, bh1, bz2, bh2,
                                  wl1, bl1, wl2, bl2, out);
}